// Round 1
// baseline (494.700 us; speedup 1.0000x reference)
//
#include <hip/hip_runtime.h>
#include <hip/hip_fp16.h>
#include <math.h>

// ---------------------------------------------------------------------------
// FeedForward: LN -> act-int8-fakequant x ternary-weight qlinear -> GELU(erf)
//              -> qlinear.  Exact-integer i8 MFMA GEMMs (32x32x32).
// h1/h2 fp16 -> exact per-tensor quantile via 32768-bin |bits| histogram.
// Shapes: x[16384,1024], w1[4096,1024], w2[1024,4096], out[16384,1024] fp32.
//
// GEMM v3: 256x256 tile, BK=64, 4-buffer LDS ring (128 KiB), depth-3 prefetch
// with counted s_waitcnt vmcnt(8) at tile boundaries (never drain-0 in steady
// state), raw s_barrier, setprio(1) around MFMA clusters, XCD-swizzled grid.
// ---------------------------------------------------------------------------

#define M_ROWS 16384
#define D_DIM  1024
#define H_DIM  4096

typedef int i32x4 __attribute__((ext_vector_type(4)));
typedef int i32x16 __attribute__((ext_vector_type(16)));

#define AS1 __attribute__((address_space(1)))
#define AS3 __attribute__((address_space(3)))

__device__ __forceinline__ void load_lds16(const void* g, void* l) {
  __builtin_amdgcn_global_load_lds((const AS1 void*)g, (AS3 void*)l, 16, 0, 0);
}

// ---------------------------------------------------------------------------
// LayerNorm: one block (256 thr) per row of 1024; fp16 output.
// ---------------------------------------------------------------------------
__device__ __forceinline__ float block_sum256(float v, float* lds) {
#pragma unroll
  for (int o = 32; o > 0; o >>= 1) v += __shfl_down(v, o, 64);
  int t = threadIdx.x;
  __syncthreads();
  if ((t & 63) == 0) lds[t >> 6] = v;
  __syncthreads();
  return lds[0] + lds[1] + lds[2] + lds[3];
}

__global__ __launch_bounds__(256) void k_layernorm(
    const float* __restrict__ x, const float* __restrict__ g,
    const float* __restrict__ b, __half* __restrict__ out) {
  __shared__ float lds[4];
  int row = blockIdx.x, t = threadIdx.x;
  float4 v = ((const float4*)(x + (size_t)row * D_DIM))[t];
  float s = v.x + v.y + v.z + v.w;
  s = block_sum256(s, lds);
  float mu = s * (1.0f / D_DIM);
  float d0 = v.x - mu, d1 = v.y - mu, d2 = v.z - mu, d3 = v.w - mu;
  float ss = d0 * d0 + d1 * d1 + d2 * d2 + d3 * d3;
  ss = block_sum256(ss, lds);
  float inv = 1.0f / sqrtf(ss * (1.0f / D_DIM) + 1e-5f);
  float4 gg = ((const float4*)g)[t];
  float4 bb = ((const float4*)b)[t];
  __half2 p0 = __floats2half2_rn(d0 * inv * gg.x + bb.x, d1 * inv * gg.y + bb.y);
  __half2 p1 = __floats2half2_rn(d2 * inv * gg.z + bb.z, d3 * inv * gg.w + bb.w);
  uint2 st;
  st.x = *(unsigned*)&p0;
  st.y = *(unsigned*)&p1;
  ((uint2*)(out + (size_t)row * D_DIM))[t] = st;
}

// ---------------------------------------------------------------------------
// Weight ternary quantization (both weights in one launch each phase)
// ---------------------------------------------------------------------------
__global__ __launch_bounds__(256) void k_absmean2(const float4* __restrict__ w1,
                                                  const float4* __restrict__ w2,
                                                  size_t n4, double* __restrict__ out) {
  int which = (blockIdx.x >= (gridDim.x >> 1)) ? 1 : 0;
  const float4* p = which ? w2 : w1;
  unsigned half_grid = gridDim.x >> 1;
  unsigned blk = blockIdx.x - which * half_grid;
  double s = 0.0;
  size_t stride = (size_t)half_grid * blockDim.x;
  for (size_t i = (size_t)blk * blockDim.x + threadIdx.x; i < n4; i += stride) {
    float4 v = p[i];
    s += (double)fabsf(v.x) + (double)fabsf(v.y) + (double)fabsf(v.z) + (double)fabsf(v.w);
  }
#pragma unroll
  for (int o = 32; o > 0; o >>= 1) s += __shfl_down(s, o, 64);
  __shared__ double ds[4];
  int t = threadIdx.x;
  if ((t & 63) == 0) ds[t >> 6] = s;
  __syncthreads();
  if (t == 0) atomicAdd(out + which, ds[0] + ds[1] + ds[2] + ds[3]);
}

__device__ __forceinline__ int tern1(float w, float gamma) {
  return (int)fminf(1.f, fmaxf(-1.f, rintf(w / gamma)));
}

__global__ __launch_bounds__(256) void k_wquant2(const float4* __restrict__ w1,
                                                 const float4* __restrict__ w2,
                                                 unsigned* __restrict__ q1,
                                                 unsigned* __restrict__ q2, size_t n4,
                                                 const double* __restrict__ sump,
                                                 double inv_n, float* __restrict__ gamma_out) {
  int which = (blockIdx.x >= (gridDim.x >> 1)) ? 1 : 0;
  const float4* w = which ? w2 : w1;
  unsigned* wq = which ? q2 : q1;
  unsigned half_grid = gridDim.x >> 1;
  unsigned blk = blockIdx.x - which * half_grid;
  float gamma = (float)(sump[which] * inv_n) + 1e-5f;
  if (blk == 0 && threadIdx.x == 0) gamma_out[which] = gamma;
  size_t stride = (size_t)half_grid * blockDim.x;
  for (size_t i = (size_t)blk * blockDim.x + threadIdx.x; i < n4; i += stride) {
    float4 v = w[i];
    int a = tern1(v.x, gamma), b = tern1(v.y, gamma), c = tern1(v.z, gamma), d = tern1(v.w, gamma);
    wq[i] = (unsigned)(a & 255) | ((unsigned)(b & 255) << 8) |
            ((unsigned)(c & 255) << 16) | ((unsigned)(d & 255) << 24);
  }
}

// ---------------------------------------------------------------------------
// Exact fp16 quantile: 32768-bin histogram over |bits| (monotone for halfs).
// ---------------------------------------------------------------------------
__global__ __launch_bounds__(512) void k_hist16(const uint4* __restrict__ p, size_t n8,
                                                unsigned* __restrict__ hist) {
  extern __shared__ unsigned h[];  // 32768 bins
  int t = threadIdx.x;
  for (int i = t; i < 32768; i += 512) h[i] = 0;
  __syncthreads();
  size_t stride = (size_t)gridDim.x * 512;
  for (size_t i = (size_t)blockIdx.x * 512 + t; i < n8; i += stride) {
    uint4 u = p[i];
    atomicAdd(&h[u.x & 0x7FFFu], 1u);
    atomicAdd(&h[(u.x >> 16) & 0x7FFFu], 1u);
    atomicAdd(&h[u.y & 0x7FFFu], 1u);
    atomicAdd(&h[(u.y >> 16) & 0x7FFFu], 1u);
    atomicAdd(&h[u.z & 0x7FFFu], 1u);
    atomicAdd(&h[(u.z >> 16) & 0x7FFFu], 1u);
    atomicAdd(&h[u.w & 0x7FFFu], 1u);
    atomicAdd(&h[(u.w >> 16) & 0x7FFFu], 1u);
  }
  __syncthreads();
  for (int i = t; i < 32768; i += 512) {
    unsigned c = h[i];
    if (c) atomicAdd(&hist[i], c);
  }
}

// scan 32768 bins; order stats a[k], a[k+1]; numpy lerp -> amax, scale
__global__ __launch_bounds__(256) void k_scanq(const unsigned* __restrict__ hist,
                                               float* __restrict__ scl,
                                               unsigned long long k, double frac) {
  __shared__ unsigned tsum[256];
  __shared__ unsigned long long pre[256];
  __shared__ unsigned vk, vk1;
  int t = threadIdx.x;
  unsigned s = 0;
  for (int j = 0; j < 128; ++j) s += hist[t * 128 + j];
  tsum[t] = s;
  __syncthreads();
  if (t == 0) {
    unsigned long long c = 0;
    for (int i = 0; i < 256; ++i) { pre[i] = c; c += tsum[i]; }
  }
  __syncthreads();
  unsigned long long base = pre[t];
  for (int j = 0; j < 128; ++j) {
    unsigned c = hist[t * 128 + j];
    if (base <= k && k < base + c) vk = t * 128 + j;
    if (base <= k + 1 && k + 1 < base + c) vk1 = t * 128 + j;
    base += c;
  }
  __syncthreads();
  if (t == 0) {
    double a = (double)__half2float(__ushort_as_half((unsigned short)vk));
    double b = (double)__half2float(__ushort_as_half((unsigned short)vk1));
    double qv = (frac >= 0.5) ? (b - (b - a) * (1.0 - frac)) : (a + (b - a) * frac);
    float amax = fmaxf((float)qv, 1e-5f);
    scl[0] = amax;
    scl[1] = 127.0f / amax;
  }
}

// ---------------------------------------------------------------------------
// Activation int8 quantization (fp16 source, 8 at a time)
// ---------------------------------------------------------------------------
__device__ __forceinline__ void unpack8(uint4 u, float* f) {
  __half2 h;
  h = *(__half2*)&u.x; f[0] = __low2float(h); f[1] = __high2float(h);
  h = *(__half2*)&u.y; f[2] = __low2float(h); f[3] = __high2float(h);
  h = *(__half2*)&u.z; f[4] = __low2float(h); f[5] = __high2float(h);
  h = *(__half2*)&u.w; f[6] = __low2float(h); f[7] = __high2float(h);
}

__device__ __forceinline__ unsigned qpack4(float a, float b, float c, float d, float s) {
  int qa = (int)fminf(127.f, fmaxf(-128.f, rintf(a * s)));
  int qb = (int)fminf(127.f, fmaxf(-128.f, rintf(b * s)));
  int qc = (int)fminf(127.f, fmaxf(-128.f, rintf(c * s)));
  int qd = (int)fminf(127.f, fmaxf(-128.f, rintf(d * s)));
  return (unsigned)(qa & 255) | ((unsigned)(qb & 255) << 8) |
         ((unsigned)(qc & 255) << 16) | ((unsigned)(qd & 255) << 24);
}

__global__ __launch_bounds__(256) void k_quant16(const uint4* __restrict__ p,
                                                 uint2* __restrict__ q, size_t n8,
                                                 const float* __restrict__ scl) {
  float s = scl[1];
  size_t stride = (size_t)gridDim.x * blockDim.x;
  for (size_t i = (size_t)blockIdx.x * blockDim.x + threadIdx.x; i < n8; i += stride) {
    float f[8];
    unpack8(p[i], f);
    uint2 r;
    r.x = qpack4(f[0], f[1], f[2], f[3], s);
    r.y = qpack4(f[4], f[5], f[6], f[7], s);
    q[i] = r;
  }
}

// ---------------------------------------------------------------------------
// GELU via Abramowitz-Stegun 7.1.26 erf (abs err 1.5e-7)
// ---------------------------------------------------------------------------
__device__ __forceinline__ float gelu_fast(float v) {
  float a = fabsf(v) * 0.70710678118654752f;
  float t = __builtin_amdgcn_rcpf(fmaf(0.3275911f, a, 1.0f));
  float p = t * fmaf(t, fmaf(t, fmaf(t, fmaf(t, 1.061405429f, -1.453152027f),
                                     1.421413741f), -0.284496736f), 0.254829592f);
  float e = __expf(-a * a);
  float er = fmaf(-p, e, 1.0f);
  float erf_s = copysignf(er, v);
  return 0.5f * v * (1.0f + erf_s);
}

// ---------------------------------------------------------------------------
// int8 GEMM v3, C = A[M,K] * B[N,K]^T.
// 256x256 tile, BK=64 bytes, 512 threads = 8 waves (2M x 4N), per-wave 128x64
// output via 4x2 of mfma_i32_32x32x32_i8.
// LDS: 4-buffer ring, 4 x (16KB A + 16KB B) = 128 KiB (dynamic).
// Pipeline: while computing tile t, stage tile t+3 (2 global_load_lds per
// phase).  Tile-boundary wait is s_waitcnt vmcnt(8): loads of tiles t+2,t+3
// stay in flight across the barrier (T3+T4); drain only at the tail.
// Swizzle: LDS dest linear (required by global_load_lds); global source
// granule pre-swizzled with slot = g ^ ((row>>1)&3) so 8 consecutive rows
// cover all 32 banks on ds_read_b128.
// setprio(1) around each MFMA cluster (T5); XCD-bijective grid swizzle (T1).
// ---------------------------------------------------------------------------
template <int K, bool GELU>
__global__ __launch_bounds__(512, 2) void k_gemm(const signed char* __restrict__ A,
                                                 const signed char* __restrict__ B,
                                                 int N, void* __restrict__ outp,
                                                 const float* __restrict__ gamma_p,
                                                 const float* __restrict__ scl) {
  constexpr int NT = K / 64;  // K-tiles of 64 bytes
  extern __shared__ __align__(16) char smem[];
  signed char* As = (signed char*)smem;           // 4 x 16384
  signed char* Bs = (signed char*)smem + 65536;   // 4 x 16384

  const int tid = threadIdx.x;
  const int lane = tid & 63;
  const int wv = tid >> 6;
  const int wr = (wv >> 2) * 128;  // wave M offset: 0 / 128
  const int wc = (wv & 3) * 64;    // wave N offset: 0/64/128/192

  // XCD-bijective swizzle (gridDim.x divisible by 8 for both GEMMs)
  const unsigned nwg = gridDim.x;
  const unsigned q8 = nwg >> 3;
  const unsigned bid = blockIdx.x;
  const unsigned swz = (bid & 7) * q8 + (bid >> 3);
  const unsigned nx = (unsigned)N >> 8;
  const int n0 = (int)(swz % nx) * 256;
  const int m0 = (int)(swz / nx) * 256;

  // --- staging: thread tid covers LDS bytes tid*16 (rows 0..127) and
  //     tid*16+8192 (rows 128..255); global granule pre-swizzled.
  const int srow0 = tid >> 2;        // 0..127
  const int srow1 = srow0 + 128;
  const int scg = (tid & 3) ^ ((srow0 >> 1) & 3);  // same for srow1 (+128 keeps (row>>1)&3)
  const signed char* aG0 = A + (size_t)(m0 + srow0) * K + scg * 16;
  const signed char* aG1 = A + (size_t)(m0 + srow1) * K + scg * 16;
  const signed char* bG0 = B + (size_t)(n0 + srow0) * K + scg * 16;
  const signed char* bG1 = B + (size_t)(n0 + srow1) * K + scg * 16;
  const int sL0 = tid * 16;
  const int sL1 = sL0 + 8192;

#define STAGE_A(t_) { const int bo_ = ((t_) & 3) * 16384;            \
    load_lds16(aG0 + (size_t)(t_) * 64, As + bo_ + sL0);             \
    load_lds16(aG1 + (size_t)(t_) * 64, As + bo_ + sL1); }
#define STAGE_B(t_) { const int bo_ = ((t_) & 3) * 16384;            \
    load_lds16(bG0 + (size_t)(t_) * 64, Bs + bo_ + sL0);             \
    load_lds16(bG1 + (size_t)(t_) * 64, Bs + bo_ + sL1); }

  // --- fragment LDS byte offsets (within one 16KB buffer)
  // row r, k-granule g (0..3; ksl*2 + lane>>5), slot = g ^ ((r>>1)&3)
  int a_off[4][2], b_off[2][2];
#pragma unroll
  for (int mi = 0; mi < 4; ++mi) {
    int am = wr + mi * 32 + (lane & 31);
#pragma unroll
    for (int ksl = 0; ksl < 2; ++ksl) {
      int g = ksl * 2 + (lane >> 5);
      a_off[mi][ksl] = am * 64 + ((g ^ ((am >> 1) & 3)) << 4);
    }
  }
#pragma unroll
  for (int ni = 0; ni < 2; ++ni) {
    int bn = wc + ni * 32 + (lane & 31);
#pragma unroll
    for (int ksl = 0; ksl < 2; ++ksl) {
      int g = ksl * 2 + (lane >> 5);
      b_off[ni][ksl] = bn * 64 + ((g ^ ((bn >> 1) & 3)) << 4);
    }
  }

  i32x16 acc[4][2];
#pragma unroll
  for (int mi = 0; mi < 4; ++mi)
#pragma unroll
    for (int ni = 0; ni < 2; ++ni) acc[mi][ni] = (i32x16)(0);

  // --- prologue: stage tiles 0,1,2 (12 loads); need tile 0 (oldest 4) done.
  STAGE_A(0); STAGE_B(0);
  STAGE_A(1); STAGE_B(1);
  STAGE_A(2); STAGE_B(2);
  asm volatile("s_waitcnt vmcnt(8)" ::: "memory");
  __builtin_amdgcn_s_barrier();

#pragma unroll 4
  for (int t = 0; t < NT; ++t) {
    const int bo = (t & 3) * 16384;
    // ---- phase 0: k-slice 0 ----
    {
      i32x4 af[4], bf[2];
#pragma unroll
      for (int mi = 0; mi < 4; ++mi) af[mi] = *(const i32x4*)(As + bo + a_off[mi][0]);
#pragma unroll
      for (int ni = 0; ni < 2; ++ni) bf[ni] = *(const i32x4*)(Bs + bo + b_off[ni][0]);
      if (t + 3 < NT) STAGE_A(t + 3);
      __builtin_amdgcn_sched_barrier(0);
      __builtin_amdgcn_s_barrier();
      __builtin_amdgcn_s_setprio(1);
#pragma unroll
      for (int mi = 0; mi < 4; ++mi)
#pragma unroll
        for (int ni = 0; ni < 2; ++ni)
          acc[mi][ni] = __builtin_amdgcn_mfma_i32_32x32x32_i8(af[mi], bf[ni], acc[mi][ni], 0, 0, 0);
      __builtin_amdgcn_s_setprio(0);
    }
    // ---- phase 1: k-slice 1 ----
    {
      i32x4 af[4], bf[2];
#pragma unroll
      for (int mi = 0; mi < 4; ++mi) af[mi] = *(const i32x4*)(As + bo + a_off[mi][1]);
#pragma unroll
      for (int ni = 0; ni < 2; ++ni) bf[ni] = *(const i32x4*)(Bs + bo + b_off[ni][1]);
      if (t + 3 < NT) STAGE_B(t + 3);
      __builtin_amdgcn_sched_barrier(0);
      __builtin_amdgcn_s_barrier();
      __builtin_amdgcn_s_setprio(1);
#pragma unroll
      for (int mi = 0; mi < 4; ++mi)
#pragma unroll
        for (int ni = 0; ni < 2; ++ni)
          acc[mi][ni] = __builtin_amdgcn_mfma_i32_32x32x32_i8(af[mi], bf[ni], acc[mi][ni], 0, 0, 0);
      __builtin_amdgcn_s_setprio(0);
    }
    // ---- tile boundary: tile t+1 loads must be complete; keep t+2/t+3 in flight
    if (t < NT - 3)       { asm volatile("s_waitcnt vmcnt(8)" ::: "memory"); }
    else if (t == NT - 3) { asm volatile("s_waitcnt vmcnt(4)" ::: "memory"); }
    else                  { asm volatile("s_waitcnt vmcnt(0)" ::: "memory"); }
    __builtin_amdgcn_s_barrier();
  }
#undef STAGE_A
#undef STAGE_B

  // C/D layout (32x32): col = lane&31, row = (reg&3) + 8*(reg>>2) + 4*(lane>>5)
  const float cs = (*gamma_p) / scl[1];
  const int col0 = n0 + wc + (lane & 31);
  const int row0 = m0 + wr + 4 * (lane >> 5);
#pragma unroll
  for (int mi = 0; mi < 4; ++mi) {
#pragma unroll
    for (int ni = 0; ni < 2; ++ni) {
      const int col = col0 + ni * 32;
#pragma unroll
      for (int reg = 0; reg < 16; ++reg) {
        const int row = row0 + mi * 32 + (reg & 3) + 8 * (reg >> 2);
        float v = cs * (float)acc[mi][ni][reg];
        size_t idx = (size_t)row * N + col;
        if (GELU) {
          ((__half*)outp)[idx] = __float2half(gelu_fast(v));
        } else {
          ((float*)outp)[idx] = v;
        }
      }
    }
  }
}

// ---------------------------------------------------------------------------
// Launcher.  Workspace layout (MB):
//   [0,128):   h2 fp16          [128,160): h1 fp16 (dead after GEMM1)
//   [160,176): xq1              [128,192): xq2 (reuses h1+xq1 after GEMM1)
//   [192,196): w1q  [196,200): w2q
//   [200,+):   hista 128K, histb 128K, wsum[2] dbl, gamma[2] f32, scl pairs
// ---------------------------------------------------------------------------
extern "C" void kernel_launch(void* const* d_in, const int* in_sizes, int n_in,
                              void* d_out, int out_size, void* d_ws, size_t ws_size,
                              hipStream_t stream) {
  const float* x = (const float*)d_in[0];
  const float* ln_g = (const float*)d_in[1];
  const float* ln_b = (const float*)d_in[2];
  const float* w1 = (const float*)d_in[3];
  const float* w2 = (const float*)d_in[4];
  float* out = (float*)d_out;

  char* ws = (char*)d_ws;
  __half* h2 = (__half*)ws;
  __half* h1 = (__half*)(ws + ((size_t)128 << 20));
  signed char* xq1 = (signed char*)(ws + ((size_t)160 << 20));
  signed char* xq2 = (signed char*)(ws + ((size_t)128 << 20));
  signed char* w1q = (signed char*)(ws + ((size_t)192 << 20));
  signed char* w2q = (signed char*)(ws + ((size_t)196 << 20));
  char* sm = ws + ((size_t)200 << 20);
  unsigned* hista = (unsigned*)sm;
  unsigned* histb = (unsigned*)(sm + (128 << 10));
  double* wsum = (double*)(sm + (256 << 10));
  float* gamma = (float*)(sm + (256 << 10) + 16);
  float* scl1 = (float*)(sm + (256 << 10) + 32);
  float* scl2 = (float*)(sm + (256 << 10) + 40);

  hipMemsetAsync(sm, 0, (256 << 10) + 64, stream);
  hipFuncSetAttribute((const void*)k_hist16, hipFuncAttributeMaxDynamicSharedMemorySize,
                      131072);
  hipFuncSetAttribute((const void*)(k_gemm<D_DIM, true>),
                      hipFuncAttributeMaxDynamicSharedMemorySize, 131072);
  hipFuncSetAttribute((const void*)(k_gemm<H_DIM, false>),
                      hipFuncAttributeMaxDynamicSharedMemorySize, 131072);

  const double qq = 1.0 - 0.005;
  const unsigned long long N1 = (unsigned long long)M_ROWS * D_DIM;
  const unsigned long long N2 = (unsigned long long)M_ROWS * H_DIM;
  double idx1 = qq * (double)(N1 - 1);
  double idx2 = qq * (double)(N2 - 1);
  unsigned long long k1 = (unsigned long long)idx1;
  unsigned long long k2 = (unsigned long long)idx2;
  double frac1 = idx1 - (double)k1;
  double frac2 = idx2 - (double)k2;

  const size_t nW4 = (size_t)H_DIM * D_DIM / 4;
  const double inv_nW = 1.0 / (double)(H_DIM * D_DIM);

  // ---- weights (fused launches) ----
  k_absmean2<<<1024, 256, 0, stream>>>((const float4*)w1, (const float4*)w2, nW4, wsum);
  k_wquant2<<<2048, 256, 0, stream>>>((const float4*)w1, (const float4*)w2,
                                      (unsigned*)w1q, (unsigned*)w2q, nW4, wsum, inv_nW, gamma);

  // ---- layernorm -> h1 fp16 ----
  k_layernorm<<<M_ROWS, 256, 0, stream>>>(x, ln_g, ln_b, h1);

  // ---- quantile 1 + quantize ----
  const size_t n8_1 = N1 / 8;
  k_hist16<<<256, 512, 131072, stream>>>((const uint4*)h1, n8_1, hista);
  k_scanq<<<1, 256, 0, stream>>>(hista, scl1, k1, frac1);
  k_quant16<<<1024, 256, 0, stream>>>((const uint4*)h1, (uint2*)xq1, n8_1, scl1);

  // ---- GEMM1: [16384,1024] x [4096,1024]^T -> gelu -> h2 fp16 ----
  k_gemm<D_DIM, true><<<(H_DIM / 256) * (M_ROWS / 256), 512, 131072, stream>>>(
      xq1, w1q, H_DIM, (void*)h2, gamma + 0, scl1);

  // ---- quantile 2 + quantize ----
  const size_t n8_2 = N2 / 8;
  k_hist16<<<256, 512, 131072, stream>>>((const uint4*)h2, n8_2, histb);
  k_scanq<<<1, 256, 0, stream>>>(histb, scl2, k2, frac2);
  k_quant16<<<2048, 256, 0, stream>>>((const uint4*)h2, (uint2*)xq2, n8_2, scl2);

  // ---- GEMM2: [16384,4096] x [1024,4096]^T -> out fp32 ----
  k_gemm<H_DIM, false><<<(D_DIM / 256) * (M_ROWS / 256), 512, 131072, stream>>>(
      xq2, w2q, D_DIM, (void*)out, gamma + 1, scl2);
}

// Round 2
// 462.367 us; speedup vs baseline: 1.0699x; 1.0699x over previous
//
#include <hip/hip_runtime.h>
#include <hip/hip_fp16.h>
#include <math.h>

// ---------------------------------------------------------------------------
// FeedForward: LN -> act-int8-fakequant x ternary-weight qlinear -> GELU(erf)
//              -> qlinear.  Exact-integer i8 MFMA GEMMs (32x32x32).
// h1/h2 fp16 -> exact per-tensor quantile via 32768-bin |bits| histogram.
// Shapes: x[16384,1024], w1[4096,1024], w2[1024,4096], out[16384,1024] fp32.
//
// GEMM v4: 256x256 tile, BK=128, 2-buffer LDS ring (128 KiB), register
// fragment ping-pong (reads for phase p+1 issued before phase p's MFMAs so
// LDS overlaps the MFMA-pipe stall), ONE vmcnt(0)+s_barrier per K-tile
// (drained loads are ~2000 cycles old -> free), setprio around MFMA
// clusters, XCD-bijective grid swizzle.
// ---------------------------------------------------------------------------

#define M_ROWS 16384
#define D_DIM  1024
#define H_DIM  4096

typedef int i32x4 __attribute__((ext_vector_type(4)));
typedef int i32x16 __attribute__((ext_vector_type(16)));

#define AS1 __attribute__((address_space(1)))
#define AS3 __attribute__((address_space(3)))

__device__ __forceinline__ void load_lds16(const void* g, void* l) {
  __builtin_amdgcn_global_load_lds((const AS1 void*)g, (AS3 void*)l, 16, 0, 0);
}

// ---------------------------------------------------------------------------
// LayerNorm: one block (256 thr) per row of 1024; fp16 output.
// ---------------------------------------------------------------------------
__device__ __forceinline__ float block_sum256(float v, float* lds) {
#pragma unroll
  for (int o = 32; o > 0; o >>= 1) v += __shfl_down(v, o, 64);
  int t = threadIdx.x;
  __syncthreads();
  if ((t & 63) == 0) lds[t >> 6] = v;
  __syncthreads();
  return lds[0] + lds[1] + lds[2] + lds[3];
}

__global__ __launch_bounds__(256) void k_layernorm(
    const float* __restrict__ x, const float* __restrict__ g,
    const float* __restrict__ b, __half* __restrict__ out) {
  __shared__ float lds[4];
  int row = blockIdx.x, t = threadIdx.x;
  float4 v = ((const float4*)(x + (size_t)row * D_DIM))[t];
  float s = v.x + v.y + v.z + v.w;
  s = block_sum256(s, lds);
  float mu = s * (1.0f / D_DIM);
  float d0 = v.x - mu, d1 = v.y - mu, d2 = v.z - mu, d3 = v.w - mu;
  float ss = d0 * d0 + d1 * d1 + d2 * d2 + d3 * d3;
  ss = block_sum256(ss, lds);
  float inv = 1.0f / sqrtf(ss * (1.0f / D_DIM) + 1e-5f);
  float4 gg = ((const float4*)g)[t];
  float4 bb = ((const float4*)b)[t];
  __half2 p0 = __floats2half2_rn(d0 * inv * gg.x + bb.x, d1 * inv * gg.y + bb.y);
  __half2 p1 = __floats2half2_rn(d2 * inv * gg.z + bb.z, d3 * inv * gg.w + bb.w);
  uint2 st;
  st.x = *(unsigned*)&p0;
  st.y = *(unsigned*)&p1;
  ((uint2*)(out + (size_t)row * D_DIM))[t] = st;
}

// ---------------------------------------------------------------------------
// Weight ternary quantization (both weights in one launch each phase)
// ---------------------------------------------------------------------------
__global__ __launch_bounds__(256) void k_absmean2(const float4* __restrict__ w1,
                                                  const float4* __restrict__ w2,
                                                  size_t n4, double* __restrict__ out) {
  int which = (blockIdx.x >= (gridDim.x >> 1)) ? 1 : 0;
  const float4* p = which ? w2 : w1;
  unsigned half_grid = gridDim.x >> 1;
  unsigned blk = blockIdx.x - which * half_grid;
  double s = 0.0;
  size_t stride = (size_t)half_grid * blockDim.x;
  for (size_t i = (size_t)blk * blockDim.x + threadIdx.x; i < n4; i += stride) {
    float4 v = p[i];
    s += (double)fabsf(v.x) + (double)fabsf(v.y) + (double)fabsf(v.z) + (double)fabsf(v.w);
  }
#pragma unroll
  for (int o = 32; o > 0; o >>= 1) s += __shfl_down(s, o, 64);
  __shared__ double ds[4];
  int t = threadIdx.x;
  if ((t & 63) == 0) ds[t >> 6] = s;
  __syncthreads();
  if (t == 0) atomicAdd(out + which, ds[0] + ds[1] + ds[2] + ds[3]);
}

__device__ __forceinline__ int tern1(float w, float gamma) {
  return (int)fminf(1.f, fmaxf(-1.f, rintf(w / gamma)));
}

__global__ __launch_bounds__(256) void k_wquant2(const float4* __restrict__ w1,
                                                 const float4* __restrict__ w2,
                                                 unsigned* __restrict__ q1,
                                                 unsigned* __restrict__ q2, size_t n4,
                                                 const double* __restrict__ sump,
                                                 double inv_n, float* __restrict__ gamma_out) {
  int which = (blockIdx.x >= (gridDim.x >> 1)) ? 1 : 0;
  const float4* w = which ? w2 : w1;
  unsigned* wq = which ? q2 : q1;
  unsigned half_grid = gridDim.x >> 1;
  unsigned blk = blockIdx.x - which * half_grid;
  float gamma = (float)(sump[which] * inv_n) + 1e-5f;
  if (blk == 0 && threadIdx.x == 0) gamma_out[which] = gamma;
  size_t stride = (size_t)half_grid * blockDim.x;
  for (size_t i = (size_t)blk * blockDim.x + threadIdx.x; i < n4; i += stride) {
    float4 v = w[i];
    int a = tern1(v.x, gamma), b = tern1(v.y, gamma), c = tern1(v.z, gamma), d = tern1(v.w, gamma);
    wq[i] = (unsigned)(a & 255) | ((unsigned)(b & 255) << 8) |
            ((unsigned)(c & 255) << 16) | ((unsigned)(d & 255) << 24);
  }
}

// ---------------------------------------------------------------------------
// Exact fp16 quantile: 32768-bin histogram over |bits| (monotone for halfs).
// ---------------------------------------------------------------------------
__global__ __launch_bounds__(512) void k_hist16(const uint4* __restrict__ p, size_t n8,
                                                unsigned* __restrict__ hist) {
  extern __shared__ unsigned h[];  // 32768 bins
  int t = threadIdx.x;
  for (int i = t; i < 32768; i += 512) h[i] = 0;
  __syncthreads();
  size_t stride = (size_t)gridDim.x * 512;
  for (size_t i = (size_t)blockIdx.x * 512 + t; i < n8; i += stride) {
    uint4 u = p[i];
    atomicAdd(&h[u.x & 0x7FFFu], 1u);
    atomicAdd(&h[(u.x >> 16) & 0x7FFFu], 1u);
    atomicAdd(&h[u.y & 0x7FFFu], 1u);
    atomicAdd(&h[(u.y >> 16) & 0x7FFFu], 1u);
    atomicAdd(&h[u.z & 0x7FFFu], 1u);
    atomicAdd(&h[(u.z >> 16) & 0x7FFFu], 1u);
    atomicAdd(&h[u.w & 0x7FFFu], 1u);
    atomicAdd(&h[(u.w >> 16) & 0x7FFFu], 1u);
  }
  __syncthreads();
  for (int i = t; i < 32768; i += 512) {
    unsigned c = h[i];
    if (c) atomicAdd(&hist[i], c);
  }
}

// scan 32768 bins; order stats a[k], a[k+1]; numpy lerp -> amax, scale
__global__ __launch_bounds__(256) void k_scanq(const unsigned* __restrict__ hist,
                                               float* __restrict__ scl,
                                               unsigned long long k, double frac) {
  __shared__ unsigned tsum[256];
  __shared__ unsigned long long pre[256];
  __shared__ unsigned vk, vk1;
  int t = threadIdx.x;
  unsigned s = 0;
  for (int j = 0; j < 128; ++j) s += hist[t * 128 + j];
  tsum[t] = s;
  __syncthreads();
  if (t == 0) {
    unsigned long long c = 0;
    for (int i = 0; i < 256; ++i) { pre[i] = c; c += tsum[i]; }
  }
  __syncthreads();
  unsigned long long base = pre[t];
  for (int j = 0; j < 128; ++j) {
    unsigned c = hist[t * 128 + j];
    if (base <= k && k < base + c) vk = t * 128 + j;
    if (base <= k + 1 && k + 1 < base + c) vk1 = t * 128 + j;
    base += c;
  }
  __syncthreads();
  if (t == 0) {
    double a = (double)__half2float(__ushort_as_half((unsigned short)vk));
    double b = (double)__half2float(__ushort_as_half((unsigned short)vk1));
    double qv = (frac >= 0.5) ? (b - (b - a) * (1.0 - frac)) : (a + (b - a) * frac);
    float amax = fmaxf((float)qv, 1e-5f);
    scl[0] = amax;
    scl[1] = 127.0f / amax;
  }
}

// ---------------------------------------------------------------------------
// Activation int8 quantization (fp16 source, 8 at a time)
// ---------------------------------------------------------------------------
__device__ __forceinline__ void unpack8(uint4 u, float* f) {
  __half2 h;
  h = *(__half2*)&u.x; f[0] = __low2float(h); f[1] = __high2float(h);
  h = *(__half2*)&u.y; f[2] = __low2float(h); f[3] = __high2float(h);
  h = *(__half2*)&u.z; f[4] = __low2float(h); f[5] = __high2float(h);
  h = *(__half2*)&u.w; f[6] = __low2float(h); f[7] = __high2float(h);
}

__device__ __forceinline__ unsigned qpack4(float a, float b, float c, float d, float s) {
  int qa = (int)fminf(127.f, fmaxf(-128.f, rintf(a * s)));
  int qb = (int)fminf(127.f, fmaxf(-128.f, rintf(b * s)));
  int qc = (int)fminf(127.f, fmaxf(-128.f, rintf(c * s)));
  int qd = (int)fminf(127.f, fmaxf(-128.f, rintf(d * s)));
  return (unsigned)(qa & 255) | ((unsigned)(qb & 255) << 8) |
         ((unsigned)(qc & 255) << 16) | ((unsigned)(qd & 255) << 24);
}

__global__ __launch_bounds__(256) void k_quant16(const uint4* __restrict__ p,
                                                 uint2* __restrict__ q, size_t n8,
                                                 const float* __restrict__ scl) {
  float s = scl[1];
  size_t stride = (size_t)gridDim.x * blockDim.x;
  for (size_t i = (size_t)blockIdx.x * blockDim.x + threadIdx.x; i < n8; i += stride) {
    float f[8];
    unpack8(p[i], f);
    uint2 r;
    r.x = qpack4(f[0], f[1], f[2], f[3], s);
    r.y = qpack4(f[4], f[5], f[6], f[7], s);
    q[i] = r;
  }
}

// ---------------------------------------------------------------------------
// GELU via Abramowitz-Stegun 7.1.26 erf (abs err 1.5e-7)
// ---------------------------------------------------------------------------
__device__ __forceinline__ float gelu_fast(float v) {
  float a = fabsf(v) * 0.70710678118654752f;
  float t = __builtin_amdgcn_rcpf(fmaf(0.3275911f, a, 1.0f));
  float p = t * fmaf(t, fmaf(t, fmaf(t, fmaf(t, 1.061405429f, -1.453152027f),
                                     1.421413741f), -0.284496736f), 0.254829592f);
  float e = __expf(-a * a);
  float er = fmaf(-p, e, 1.0f);
  float erf_s = copysignf(er, v);
  return 0.5f * v * (1.0f + erf_s);
}

// ---------------------------------------------------------------------------
// int8 GEMM v4, C = A[M,K] * B[N,K]^T.
// 256x256 tile, BK=128 bytes, 512 threads = 8 waves (2M x 4N), per-wave
// 128x64 output via 4x2 of mfma_i32_32x32x32_i8, 4 k-slices per tile.
// LDS: 2-buffer ring, 2 x (32KB A + 32KB B) = 128 KiB dynamic.
// Register fragment ping-pong: phase p issues ds_reads for phase p+1's
// fragments, then stall-issues phase p's 8 MFMAs -> LDS reads execute during
// the MFMA-pipe stall (structural LDS/MFMA overlap; both pipes ~balanced at
// this tiling).  ONE vmcnt(0)+s_barrier per tile: vmcnt is per-wave, so the
// barrier publishes all waves' global_load_lds completions; drained loads are
// ~2000 cycles old so the wait is free.  Cross-tile fragment prefetch reads
// the buffer not targeted by the next STAGE (WAR-safe).
// Swizzle: LDS row = 128 B (8 granules); slot = g ^ (row&7); source-side
// pre-swizzle keeps global_load_lds dest linear.
// ---------------------------------------------------------------------------
template <int K, bool GELU>
__global__ __launch_bounds__(512, 2) void k_gemm(const signed char* __restrict__ A,
                                                 const signed char* __restrict__ B,
                                                 int N, void* __restrict__ outp,
                                                 const float* __restrict__ gamma_p,
                                                 const float* __restrict__ scl) {
  constexpr int NT = K / 128;  // K-tiles of 128 bytes
  extern __shared__ __align__(16) char smem[];
  signed char* As = (signed char*)smem;           // 2 x 32768
  signed char* Bs = (signed char*)smem + 65536;   // 2 x 32768

  const int tid = threadIdx.x;
  const int lane = tid & 63;
  const int wv = tid >> 6;
  const int wr = (wv >> 2) * 128;  // wave M offset: 0 / 128
  const int wc = (wv & 3) * 64;    // wave N offset: 0/64/128/192

  // XCD-bijective swizzle (gridDim.x divisible by 8 for both GEMMs)
  const unsigned nwg = gridDim.x;
  const unsigned q8 = nwg >> 3;
  const unsigned bid = blockIdx.x;
  const unsigned swz = (bid & 7) * q8 + (bid >> 3);
  const unsigned nx = (unsigned)N >> 8;
  const int n0 = (int)(swz % nx) * 256;
  const int m0 = (int)(swz / nx) * 256;

  // --- staging: 4 granules/thread/matrix.  Linear LDS granule g_lin holds
  //     global granule cg = (g_lin&7) ^ (row&7), row = g_lin>>3.
  const signed char* aG[4];
  const signed char* bG[4];
  int sL[4];
#pragma unroll
  for (int j = 0; j < 4; ++j) {
    int g_lin = j * 512 + tid;
    int row = g_lin >> 3;
    int cg = (g_lin & 7) ^ (row & 7);
    aG[j] = A + (size_t)(m0 + row) * K + cg * 16;
    bG[j] = B + (size_t)(n0 + row) * K + cg * 16;
    sL[j] = g_lin * 16;
  }

#define STAGE(t_)                                              \
  {                                                            \
    const size_t ko_ = (size_t)(t_) * 128;                     \
    const int bo_ = ((t_) & 1) << 15;                          \
    _Pragma("unroll") for (int j = 0; j < 4; ++j)              \
        load_lds16(aG[j] + ko_, As + bo_ + sL[j]);             \
    _Pragma("unroll") for (int j = 0; j < 4; ++j)              \
        load_lds16(bG[j] + ko_, Bs + bo_ + sL[j]);             \
  }

  // --- fragment LDS byte offsets: row r, phase p, k-granule g = 2p+(lane>>5),
  //     slot = g ^ (r&7); byte = r*128 + slot*16
  int a_off[4][4], b_off[2][4];
#pragma unroll
  for (int mi = 0; mi < 4; ++mi) {
    int am = wr + mi * 32 + (lane & 31);
#pragma unroll
    for (int p = 0; p < 4; ++p) {
      int g = p * 2 + (lane >> 5);
      a_off[mi][p] = am * 128 + ((g ^ (am & 7)) << 4);
    }
  }
#pragma unroll
  for (int ni = 0; ni < 2; ++ni) {
    int bn = wc + ni * 32 + (lane & 31);
#pragma unroll
    for (int p = 0; p < 4; ++p) {
      int g = p * 2 + (lane >> 5);
      b_off[ni][p] = bn * 128 + ((g ^ (bn & 7)) << 4);
    }
  }

#define RD(fa, fb, bo_, p_)                                      \
  {                                                              \
    _Pragma("unroll") for (int mi = 0; mi < 4; ++mi)             \
        fa[mi] = *(const i32x4*)(As + (bo_) + a_off[mi][p_]);    \
    _Pragma("unroll") for (int ni = 0; ni < 2; ++ni)             \
        fb[ni] = *(const i32x4*)(Bs + (bo_) + b_off[ni][p_]);    \
  }

#define MM(fa, fb)                                                            \
  {                                                                           \
    __builtin_amdgcn_s_setprio(1);                                            \
    _Pragma("unroll") for (int mi = 0; mi < 4; ++mi)                          \
        _Pragma("unroll") for (int ni = 0; ni < 2; ++ni)                      \
            acc[mi][ni] = __builtin_amdgcn_mfma_i32_32x32x32_i8(              \
                fa[mi], fb[ni], acc[mi][ni], 0, 0, 0);                        \
    __builtin_amdgcn_s_setprio(0);                                            \
  }

  i32x16 acc[4][2];
#pragma unroll
  for (int mi = 0; mi < 4; ++mi)
#pragma unroll
    for (int ni = 0; ni < 2; ++ni) acc[mi][ni] = (i32x16)(0);

  i32x4 fA0[4], fB0[2], fA1[4], fB1[2];

  // --- prologue: stage tiles 0,1 (16 loads); wait own tile-0 loads, barrier
  //     publishes all waves' tile-0 loads; read (0,0) fragments.
  STAGE(0);
  STAGE(1);
  asm volatile("s_waitcnt vmcnt(8)" ::: "memory");
  __builtin_amdgcn_s_barrier();
  RD(fA0, fB0, 0, 0);

#pragma unroll 2
  for (int t = 0; t < NT; ++t) {
    const int bo = (t & 1) << 15;
    if (t >= 1 && t + 1 < NT) STAGE(t + 1);  // -> buffer bo^1 (tile t-1 reads done)
    // phase 0: read (t,1), MFMA (t,0)
    RD(fA1, fB1, bo, 1);
    __builtin_amdgcn_sched_barrier(0);
    MM(fA0, fB0);
    __builtin_amdgcn_sched_barrier(0);
    // phase 1: read (t,2), MFMA (t,1)
    RD(fA0, fB0, bo, 2);
    __builtin_amdgcn_sched_barrier(0);
    MM(fA1, fB1);
    __builtin_amdgcn_sched_barrier(0);
    // phase 2: read (t,3), MFMA (t,2)
    RD(fA1, fB1, bo, 3);
    __builtin_amdgcn_sched_barrier(0);
    MM(fA0, fB0);
    __builtin_amdgcn_sched_barrier(0);
    // phase 3: MFMA (t,3), then tile boundary
    MM(fA1, fB1);
    if (t + 1 < NT) {
      // own STAGE(t+1) loads were issued ~3 phases ago -> wait is free
      asm volatile("s_waitcnt vmcnt(0)" ::: "memory");
      __builtin_amdgcn_s_barrier();  // publish all waves' loads; all buffer-bo
                                     // reads already consumed by MFMAs above
      RD(fA0, fB0, bo ^ 32768, 0);   // prefetch (t+1,0); next STAGE hits bo
    }
  }
#undef STAGE
#undef RD
#undef MM

  // C/D layout (32x32): col = lane&31, row = (reg&3) + 8*(reg>>2) + 4*(lane>>5)
  const float cs = (*gamma_p) / scl[1];
  const int col0 = n0 + wc + (lane & 31);
  const int row0 = m0 + wr + 4 * (lane >> 5);
#pragma unroll
  for (int mi = 0; mi < 4; ++mi) {
#pragma unroll
    for (int ni = 0; ni < 2; ++ni) {
      const int col = col0 + ni * 32;
#pragma unroll
      for (int reg = 0; reg < 16; ++reg) {
        const int row = row0 + mi * 32 + (reg & 3) + 8 * (reg >> 2);
        float v = cs * (float)acc[mi][ni][reg];
        size_t idx = (size_t)row * N + col;
        if (GELU) {
          ((__half*)outp)[idx] = __float2half(gelu_fast(v));
        } else {
          ((float*)outp)[idx] = v;
        }
      }
    }
  }
}

// ---------------------------------------------------------------------------
// Launcher.  Workspace layout (MB):
//   [0,128):   h2 fp16          [128,160): h1 fp16 (dead after GEMM1)
//   [160,176): xq1              [128,192): xq2 (reuses h1+xq1 after GEMM1)
//   [192,196): w1q  [196,200): w2q
//   [200,+):   hista 128K, histb 128K, wsum[2] dbl, gamma[2] f32, scl pairs
// ---------------------------------------------------------------------------
extern "C" void kernel_launch(void* const* d_in, const int* in_sizes, int n_in,
                              void* d_out, int out_size, void* d_ws, size_t ws_size,
                              hipStream_t stream) {
  const float* x = (const float*)d_in[0];
  const float* ln_g = (const float*)d_in[1];
  const float* ln_b = (const float*)d_in[2];
  const float* w1 = (const float*)d_in[3];
  const float* w2 = (const float*)d_in[4];
  float* out = (float*)d_out;

  char* ws = (char*)d_ws;
  __half* h2 = (__half*)ws;
  __half* h1 = (__half*)(ws + ((size_t)128 << 20));
  signed char* xq1 = (signed char*)(ws + ((size_t)160 << 20));
  signed char* xq2 = (signed char*)(ws + ((size_t)128 << 20));
  signed char* w1q = (signed char*)(ws + ((size_t)192 << 20));
  signed char* w2q = (signed char*)(ws + ((size_t)196 << 20));
  char* sm = ws + ((size_t)200 << 20);
  unsigned* hista = (unsigned*)sm;
  unsigned* histb = (unsigned*)(sm + (128 << 10));
  double* wsum = (double*)(sm + (256 << 10));
  float* gamma = (float*)(sm + (256 << 10) + 16);
  float* scl1 = (float*)(sm + (256 << 10) + 32);
  float* scl2 = (float*)(sm + (256 << 10) + 40);

  hipMemsetAsync(sm, 0, (256 << 10) + 64, stream);
  hipFuncSetAttribute((const void*)k_hist16, hipFuncAttributeMaxDynamicSharedMemorySize,
                      131072);
  hipFuncSetAttribute((const void*)(k_gemm<D_DIM, true>),
                      hipFuncAttributeMaxDynamicSharedMemorySize, 131072);
  hipFuncSetAttribute((const void*)(k_gemm<H_DIM, false>),
                      hipFuncAttributeMaxDynamicSharedMemorySize, 131072);

  const double qq = 1.0 - 0.005;
  const unsigned long long N1 = (unsigned long long)M_ROWS * D_DIM;
  const unsigned long long N2 = (unsigned long long)M_ROWS * H_DIM;
  double idx1 = qq * (double)(N1 - 1);
  double idx2 = qq * (double)(N2 - 1);
  unsigned long long k1 = (unsigned long long)idx1;
  unsigned long long k2 = (unsigned long long)idx2;
  double frac1 = idx1 - (double)k1;
  double frac2 = idx2 - (double)k2;

  const size_t nW4 = (size_t)H_DIM * D_DIM / 4;
  const double inv_nW = 1.0 / (double)(H_DIM * D_DIM);

  // ---- weights (fused launches) ----
  k_absmean2<<<1024, 256, 0, stream>>>((const float4*)w1, (const float4*)w2, nW4, wsum);
  k_wquant2<<<2048, 256, 0, stream>>>((const float4*)w1, (const float4*)w2,
                                      (unsigned*)w1q, (unsigned*)w2q, nW4, wsum, inv_nW, gamma);

  // ---- layernorm -> h1 fp16 ----
  k_layernorm<<<M_ROWS, 256, 0, stream>>>(x, ln_g, ln_b, h1);

  // ---- quantile 1 + quantize ----
  const size_t n8_1 = N1 / 8;
  k_hist16<<<256, 512, 131072, stream>>>((const uint4*)h1, n8_1, hista);
  k_scanq<<<1, 256, 0, stream>>>(hista, scl1, k1, frac1);
  k_quant16<<<1024, 256, 0, stream>>>((const uint4*)h1, (uint2*)xq1, n8_1, scl1);

  // ---- GEMM1: [16384,1024] x [4096,1024]^T -> gelu -> h2 fp16 ----
  k_gemm<D_DIM, true><<<(H_DIM / 256) * (M_ROWS / 256), 512, 131072, stream>>>(
      xq1, w1q, H_DIM, (void*)h2, gamma + 0, scl1);

  // ---- quantile 2 + quantize ----
  const size_t n8_2 = N2 / 8;
  k_hist16<<<256, 512, 131072, stream>>>((const uint4*)h2, n8_2, histb);
  k_scanq<<<1, 256, 0, stream>>>(histb, scl2, k2, frac2);
  k_quant16<<<2048, 256, 0, stream>>>((const uint4*)h2, (uint2*)xq2, n8_2, scl2);

  // ---- GEMM2: [16384,4096] x [1024,4096]^T -> out fp32 ----
  k_gemm<H_DIM, false><<<(D_DIM / 256) * (M_ROWS / 256), 512, 131072, stream>>>(
      xq2, w2q, D_DIM, (void*)out, gamma + 1, scl2);
}